// Round 12
// baseline (308.598 us; speedup 1.0000x reference)
//
#include <hip/hip_runtime.h>
#include <hip/hip_bf16.h>
#include <stdint.h>

#define SW 4096
#define NH 32
#define NKV 8
#define GROUP 4
#define HD 128
#define HIDDEN 4096
#define BB 32
#define NQKV ((NH + 2*NKV)*HD)   // 6144
#define CH 512                   // positions per attention chunk
#define CHP (CH + 4)             // padded row for scl
#define NCH 8                    // max chunks (SW/CH)

#if defined(__has_builtin)
#if __has_builtin(__builtin_amdgcn_global_load_lds)
#define HAS_GLL 1
#endif
#endif
#ifndef HAS_GLL
#define HAS_GLL 0
#endif

// ---------------- LDS-staged K-split GEMM ----------------
// W-staging via global_load_lds (dest = wave-uniform base + lane*16: wave w stages
// k-row (i*256+t)>>6, lane c = t&63 -> lds k*1024B + c*16B, src contiguous per lane).
template<int NW>
__global__ __launch_bounds__(256)
void gemm_f32(const float* __restrict__ A, const float* __restrict__ W,
              float* __restrict__ part, int kchunk) {
    const int n0 = blockIdx.x * 256;
    const int K0 = blockIdx.y * kchunk;
    const int t = threadIdx.x;
    const int tm = t >> 6;
    const int tn = t & 63;
    __shared__ float a_lds[32*36];
    __shared__ float w_lds[32*256];

    float acc[8][4];
    #pragma unroll
    for (int i = 0; i < 8; ++i)
        #pragma unroll
        for (int j = 0; j < 4; ++j) acc[i][j] = 0.f;

    for (int ks = 0; ks < kchunk; ks += 32) {
        {
            int m = t & 31, kl = t >> 5;
            #pragma unroll
            for (int i = 0; i < 4; ++i) {
                int k = kl + i*8;
                a_lds[k*36 + m] = A[(size_t)m*HIDDEN + K0 + ks + k];
            }
        }
#if HAS_GLL
        {
            #pragma unroll
            for (int i = 0; i < 8; ++i) {
                int j = t + i*256;
                int k = j >> 6, c = j & 63;
                __builtin_amdgcn_global_load_lds(
                    (const __attribute__((address_space(1))) void*)(W + (size_t)(K0 + ks + k)*NW + n0 + (c<<2)),
                    (__attribute__((address_space(3))) void*)(&w_lds[k*256 + (c<<2)]),
                    16, 0, 0);
            }
        }
#else
        {
            #pragma unroll
            for (int i = 0; i < 8; ++i) {
                int j = t + i*256;
                int k = j >> 6, c = j & 63;
                const float4* src = (const float4*)(W + (size_t)(K0 + ks + k)*NW + n0);
                *(float4*)&w_lds[k*256 + c*4] = src[c];
            }
        }
#endif
        __syncthreads();
        #pragma unroll 8
        for (int k = 0; k < 32; ++k) {
            float4 a0 = *(const float4*)&a_lds[k*36 + tm*8];
            float4 a1 = *(const float4*)&a_lds[k*36 + tm*8 + 4];
            float4 w  = *(const float4*)&w_lds[k*256 + tn*4];
            float am[8] = {a0.x,a0.y,a0.z,a0.w,a1.x,a1.y,a1.z,a1.w};
            #pragma unroll
            for (int mi = 0; mi < 8; ++mi) {
                acc[mi][0] += am[mi]*w.x;
                acc[mi][1] += am[mi]*w.y;
                acc[mi][2] += am[mi]*w.z;
                acc[mi][3] += am[mi]*w.w;
            }
        }
        __syncthreads();
    }
    float* dst = part + (size_t)blockIdx.y*32*NW;
    #pragma unroll
    for (int mi = 0; mi < 8; ++mi) {
        int m = tm*8 + mi;
        float4 v = make_float4(acc[mi][0], acc[mi][1], acc[mi][2], acc[mi][3]);
        *(float4*)&dst[(size_t)m*NW + n0 + tn*4] = v;
    }
}

template<int NW>
__global__ __launch_bounds__(256)
void reduce_part(const float* __restrict__ part, float* __restrict__ out, int ksplit) {
    int idx = blockIdx.x*256 + threadIdx.x;
    if (idx >= 32*NW) return;
    float s = 0.f;
    for (int i = 0; i < ksplit; ++i) s += part[(size_t)i*32*NW + idx];
    out[idx] = s;
}

// ---------------- RoPE fused with K-split reduction of part1 ----------------
__global__ __launch_bounds__(256)
void rope_red(const float* __restrict__ part1, int KS, const float* __restrict__ rot,
              float* __restrict__ qrot, float* __restrict__ krot) {
    const int b = blockIdx.x;
    const int hbase = blockIdx.y * 8;
    const int t = threadIdx.x;
    __shared__ float Rl[64 * HD];
    __shared__ float qin[8 * HD];
    {
        const float* qsrc = part1 + (size_t)b * NQKV + (size_t)hbase * HD;
        float4 a = make_float4(0.f, 0.f, 0.f, 0.f);
        for (int i = 0; i < KS; ++i) {
            float4 v = ((const float4*)(qsrc + (size_t)i * 32 * NQKV))[t];
            a.x += v.x; a.y += v.y; a.z += v.z; a.w += v.w;
        }
        ((float4*)qin)[t] = a;
    }

    float acc[4] = {0.f, 0.f, 0.f, 0.f};
    for (int pass = 0; pass < 2; ++pass) {
        const float4* rsrc = (const float4*)(rot + (size_t)b * HD * HD + pass * 64 * HD);
        #pragma unroll
        for (int i = 0; i < 8; ++i) {
            int j = t + i * 256;
            ((float4*)Rl)[j] = rsrc[j];
        }
        __syncthreads();
        #pragma unroll
        for (int i = 0; i < 4; ++i) {
            int o = t + i * 256;
            int h = o >> 7, e = o & 127;
            float s = 0.f;
            for (int d = 0; d < 64; ++d) s += qin[h * HD + pass * 64 + d] * Rl[d * HD + e];
            acc[i] += s;
        }
        __syncthreads();
    }
    #pragma unroll
    for (int i = 0; i < 4; ++i) {
        int o = t + i * 256;
        int h = o >> 7, e = o & 127;
        int hh = hbase + h;
        if (hh < NH) qrot[((size_t)b * NH + hh) * HD + e] = acc[i];
        else         krot[((size_t)b * NKV + (hh - NH)) * HD + e] = acc[i];
    }
}

__device__ __forceinline__ void window_of(int sp, int& lo, int& hi, int& cur) {
    cur = ((sp % SW) + SW) % SW;
    if (sp < SW) { lo = 0; hi = sp + 1; } else { lo = cur; hi = SW - cur; }
}

// ---------------- flash-decode attention v3: q in registers, nc-bounded loops ----------------
// block = (b*8+kv, chunk of 512), 256 threads.
// partial layout per (bkv, c): o[4*128], m[4], l[4]  => 520 floats
__global__ __launch_bounds__(256)
void attn_chunk(const float* __restrict__ qrot, const float* __restrict__ krot,
                const float* __restrict__ part1, int KS,
                const float* __restrict__ ck, const float* __restrict__ cv,
                const int* __restrict__ spp, float* __restrict__ attnp) {
    const int bkv = blockIdx.x;
    const int b = bkv >> 3, kv = bkv & 7;
    const int c = blockIdx.y;
    const int t = threadIdx.x;
    int lo, hi, cur;
    window_of(spp[0], lo, hi, cur);
    const int n = hi - lo;
    const int base0 = c * CH;
    if (base0 >= n) return;                       // block-uniform exit
    const int nc = (n - base0 < CH) ? (n - base0) : CH;
    const size_t kvoff = (size_t)(b * NKV + kv) * SW * HD;
    const float scale = 0.08838834764831845f;     // 1/sqrt(128)

    __shared__ float q_lds[GROUP * HD];           // 2KB
    __shared__ float scl[GROUP * CHP];            // 8.25KB scores -> probs (padded)
    __shared__ float vnew[HD];                    // 0.5KB
    __shared__ float mg[GROUP], lg[GROUP];
    __shared__ float pp[4][GROUP][HD];            // 8KB

    {
        const size_t qoff = ((size_t)b * NH + kv * GROUP) * HD;
        q_lds[t]       = qrot[qoff + t];
        q_lds[256 + t] = qrot[qoff + 256 + t];
    }
    if (t < HD) {   // vnew = sum over K-split slices (L2-resident)
        const float* vsrc = part1 + (size_t)b * NQKV + (size_t)(NH + NKV) * HD + kv * HD + t;
        float s = 0.f;
        for (int i = 0; i < KS; ++i) s += vsrc[(size_t)i * 32 * NQKV];
        vnew[t] = s;
    }
    __syncthreads();

    const int iters = (nc + 31) >> 5;             // score iterations actually needed

    // ---- scores: 8 lanes per position; q hoisted to registers (zero LDS in loop) ----
    {
        const int dsl  = t & 7;                   // d-slice: d = j*32 + dsl*4
        const int posw = (t >> 3) & 7;            // position within wave's 8
        const int w    = t >> 6;                  // wave id
        float4 qreg[GROUP][4];
        #pragma unroll
        for (int g = 0; g < GROUP; ++g)
            #pragma unroll
            for (int j = 0; j < 4; ++j)
                qreg[g][j] = *(const float4*)&q_lds[g*HD + j*32 + dsl*4];

        const float* krow = krot + ((size_t)b * NKV + kv) * HD;
        #pragma unroll 1
        for (int it = 0; it < iters; ++it) {      // 32 positions/block each
            const int r = it*32 + w*8 + posw;
            const bool valid = (r < nc);
            float s0 = 0.f, s1 = 0.f, s2 = 0.f, s3 = 0.f;
            if (valid) {
                const int p = lo + base0 + r;
                const float* kbase = (p == cur) ? krow : (ck + kvoff + (size_t)p * HD);
                #pragma unroll
                for (int j = 0; j < 4; ++j) {
                    float4 kk = *(const float4*)&kbase[j*32 + dsl*4];
                    s0 += kk.x*qreg[0][j].x + kk.y*qreg[0][j].y + kk.z*qreg[0][j].z + kk.w*qreg[0][j].w;
                    s1 += kk.x*qreg[1][j].x + kk.y*qreg[1][j].y + kk.z*qreg[1][j].z + kk.w*qreg[1][j].w;
                    s2 += kk.x*qreg[2][j].x + kk.y*qreg[2][j].y + kk.z*qreg[2][j].z + kk.w*qreg[2][j].w;
                    s3 += kk.x*qreg[3][j].x + kk.y*qreg[3][j].y + kk.z*qreg[3][j].z + kk.w*qreg[3][j].w;
                }
            }
            // reduce across the 8 d-slice lanes
            s0 += __shfl_xor(s0, 1); s0 += __shfl_xor(s0, 2); s0 += __shfl_xor(s0, 4);
            s1 += __shfl_xor(s1, 1); s1 += __shfl_xor(s1, 2); s1 += __shfl_xor(s1, 4);
            s2 += __shfl_xor(s2, 1); s2 += __shfl_xor(s2, 2); s2 += __shfl_xor(s2, 4);
            s3 += __shfl_xor(s3, 1); s3 += __shfl_xor(s3, 2); s3 += __shfl_xor(s3, 4);
            float sg = (dsl == 0) ? s0 : (dsl == 1) ? s1 : (dsl == 2) ? s2 : s3;
            if (dsl < GROUP)
                scl[dsl * CHP + r] = valid ? sg * scale : -3.0e38f;
        }
        // prefill tail region not covered by the bounded loop
        for (int r = (iters << 5) + t; r < CH; r += 256)
            #pragma unroll
            for (int g = 0; g < GROUP; ++g) scl[g*CHP + r] = -3.0e38f;
    }
    __syncthreads();

    // ---- softmax partials: wave w reduces group w ----
    {
        const int w = t >> 6, l = t & 63;
        float v[8];
        float m = -3.0e38f;
        #pragma unroll
        for (int j = 0; j < 8; ++j) {
            v[j] = scl[w*CHP + l + 64*j];
            m = fmaxf(m, v[j]);
        }
        #pragma unroll
        for (int off = 32; off; off >>= 1) m = fmaxf(m, __shfl_xor(m, off));
        float ss = 0.f;
        #pragma unroll
        for (int j = 0; j < 8; ++j) {
            float e = __expf(v[j] - m);
            scl[w*CHP + l + 64*j] = e;
            ss += e;
        }
        #pragma unroll
        for (int off = 32; off; off >>= 1) ss += __shfl_xor(ss, off);
        if (l == 0) { mg[w] = m; lg[w] = ss; }
    }
    __syncthreads();

    // ---- partial PV: wave rg owns rows [rg*128, +128) bounded by nc; b128 prob broadcasts ----
    {
        const int d2 = (t & 63) * 2, rg = t >> 6;
        const int r0 = rg * (CH/4);
        const int nrows = (nc > r0) ? ((nc - r0 < CH/4) ? nc - r0 : CH/4) : 0;
        const int imax = (nrows + 3) >> 2;
        const float2 vn2 = *(const float2*)&vnew[d2];
        float a0[GROUP], a1[GROUP];
        #pragma unroll
        for (int g = 0; g < GROUP; ++g) { a0[g] = 0.f; a1[g] = 0.f; }
        #pragma unroll 1
        for (int i = 0; i < imax; ++i) {          // 4 rows each
            const int r = r0 + i*4;
            float4 pr[GROUP];
            #pragma unroll
            for (int g = 0; g < GROUP; ++g)
                pr[g] = *(const float4*)&scl[g*CHP + r];
            #pragma unroll
            for (int k = 0; k < 4; ++k) {
                const int rr = r + k;
                const int p = lo + base0 + rr;
                float2 v;
                if (rr >= nc)      v = make_float2(0.f, 0.f);
                else if (p == cur) v = vn2;
                else               v = *(const float2*)&cv[kvoff + (size_t)p * HD + d2];
                const float p0 = (k == 0) ? pr[0].x : (k == 1) ? pr[0].y : (k == 2) ? pr[0].z : pr[0].w;
                const float p1 = (k == 0) ? pr[1].x : (k == 1) ? pr[1].y : (k == 2) ? pr[1].z : pr[1].w;
                const float p2 = (k == 0) ? pr[2].x : (k == 1) ? pr[2].y : (k == 2) ? pr[2].z : pr[2].w;
                const float p3 = (k == 0) ? pr[3].x : (k == 1) ? pr[3].y : (k == 2) ? pr[3].z : pr[3].w;
                a0[0] += p0 * v.x; a1[0] += p0 * v.y;
                a0[1] += p1 * v.x; a1[1] += p1 * v.y;
                a0[2] += p2 * v.x; a1[2] += p2 * v.y;
                a0[3] += p3 * v.x; a1[3] += p3 * v.y;
            }
        }
        #pragma unroll
        for (int g = 0; g < GROUP; ++g) {
            pp[rg][g][d2]     = a0[g];
            pp[rg][g][d2 + 1] = a1[g];
        }
    }
    __syncthreads();
    {
        float* op = attnp + ((size_t)bkv * NCH + c) * 520;
        #pragma unroll
        for (int j = 0; j < 2; ++j) {
            int v = t + 256*j;
            int g = v >> 7, d = v & 127;
            op[g * HD + d] = pp[0][g][d] + pp[1][g][d] + pp[2][g][d] + pp[3][g][d];
        }
        if (t < GROUP) {
            op[512 + t] = mg[t];
            op[516 + t] = lg[t];
        }
    }
}

// merge chunk partials: out = sum_c exp(m_c - M) o_c / sum_c exp(m_c - M) l_c
__global__ __launch_bounds__(512)
void attn_reduce(const float* __restrict__ attnp, const int* __restrict__ spp,
                 float* __restrict__ aout) {
    const int bkv = blockIdx.x;
    const int b = bkv >> 3, kv = bkv & 7;
    const int g = threadIdx.x >> 7, d = threadIdx.x & 127;
    int lo, hi, cur;
    window_of(spp[0], lo, hi, cur);
    const int n = hi - lo;
    const int nch = (n + CH - 1) / CH;
    float M = -3.0e38f;
    for (int c = 0; c < nch; ++c)
        M = fmaxf(M, attnp[((size_t)bkv * NCH + c) * 520 + 512 + g]);
    float L = 0.f, O = 0.f;
    for (int c = 0; c < nch; ++c) {
        const float* op = attnp + ((size_t)bkv * NCH + c) * 520;
        float w = __expf(op[512 + g] - M);
        L += w * op[516 + g];
        O += w * op[g * HD + d];
    }
    aout[(size_t)b * NH * HD + (size_t)(kv * GROUP + g) * HD + d] = O / L;
}

// ---------------- fallback single-block attention (known-good round-6 path) ----------------
__global__ __launch_bounds__(512)
void attn_kernel(const float* __restrict__ qrot, const float* __restrict__ krot,
                 const float* __restrict__ qkv,
                 const float* __restrict__ ck, const float* __restrict__ cv,
                 const int* __restrict__ spp, float* __restrict__ aout) {
    const int b = blockIdx.x >> 3, kv = blockIdx.x & 7;
    const int t = threadIdx.x;
    int lo, hi, cur;
    window_of(spp[0], lo, hi, cur);
    const int n = hi - lo;
    const size_t kvoff = (size_t)(b * NKV + kv) * SW * HD;
    const float scale = 0.08838834764831845f;

    __shared__ float sc[GROUP * 2304];
    __shared__ float q_lds[GROUP * HD];
    __shared__ float redb[512];
    __shared__ float ssum_s[GROUP];

    q_lds[t] = qrot[((size_t)b * NH + kv * GROUP) * HD + t];
    __syncthreads();

    for (int i = t; i < n; i += 512) {
        int p = lo + i;
        float s[GROUP] = {0.f, 0.f, 0.f, 0.f};
        if (p == cur) {
            const float* kr = krot + ((size_t)b * NKV + kv) * HD;
            for (int d = 0; d < HD; ++d) {
                float kd = kr[d];
                #pragma unroll
                for (int g = 0; g < GROUP; ++g) s[g] += kd * q_lds[g * HD + d];
            }
        } else {
            const float* kp = ck + kvoff + (size_t)p * HD;
            for (int c = 0; c < 32; ++c) {
                float4 kk = ((const float4*)kp)[c];
                #pragma unroll
                for (int g = 0; g < GROUP; ++g)
                    s[g] += kk.x * q_lds[g * HD + c * 4] + kk.y * q_lds[g * HD + c * 4 + 1]
                          + kk.z * q_lds[g * HD + c * 4 + 2] + kk.w * q_lds[g * HD + c * 4 + 3];
            }
        }
        #pragma unroll
        for (int g = 0; g < GROUP; ++g)
            sc[g * 2304 + i] = s[g] * scale;
    }
    __syncthreads();

    for (int g = 0; g < GROUP; ++g) {
        float m = -3.0e38f;
        for (int i = t; i < n; i += 512) m = fmaxf(m, sc[g * 2304 + i]);
        redb[t] = m;
        __syncthreads();
        for (int w = 256; w > 0; w >>= 1) {
            if (t < w) redb[t] = fmaxf(redb[t], redb[t + w]);
            __syncthreads();
        }
        float mx = redb[0];
        __syncthreads();
        float s = 0.f;
        for (int i = t; i < n; i += 512) {
            float e = __expf(sc[g * 2304 + i] - mx);
            sc[g * 2304 + i] = e;
            s += e;
        }
        redb[t] = s;
        __syncthreads();
        for (int w = 256; w > 0; w >>= 1) {
            if (t < w) redb[t] += redb[t + w];
            __syncthreads();
        }
        if (t == 0) ssum_s[g] = redb[0];
        __syncthreads();
    }

    {
        const int g = t >> 7, d = t & 127;
        const float vn = qkv[(size_t)b * NQKV + (size_t)(NH + NKV) * HD + kv * HD + d];
        float acc = 0.f;
        for (int r = 0; r < n; ++r) {
            int p = lo + r;
            float v = (p == cur) ? vn : cv[kvoff + (size_t)p * HD + d];
            acc += sc[g * 2304 + r] * v;
        }
        aout[(size_t)b * NH * HD + (size_t)(kv * GROUP + g) * HD + d] = acc / ssum_s[g];
    }
}

extern "C" void kernel_launch(void* const* d_in, const int* in_sizes, int n_in,
                              void* d_out, int out_size, void* d_ws, size_t ws_size,
                              hipStream_t stream) {
    (void)out_size;
    static const long long CS[8] = {131072LL, 524288LL, 4194304LL, 134217728LL,
                                    134217728LL, 25165824LL, 16777216LL, 1LL};
    const void* Pp[8];
    bool canonical = (n_in == 8);
    if (canonical)
        for (int i = 0; i < 8; ++i)
            if ((long long)in_sizes[i] != CS[i]) { canonical = false; break; }
    if (canonical) {
        for (int i = 0; i < 8; ++i) Pp[i] = d_in[i];
    } else {
        bool used[64] = {false};
        for (int j = 0; j < 8; ++j) {
            Pp[j] = d_in[0];
            for (int i = 0; i < n_in && i < 64; ++i)
                if (!used[i] && (long long)in_sizes[i] == CS[j]) { used[i] = true; Pp[j] = d_in[i]; break; }
        }
    }

    const float* x    = (const float*)Pp[0];
    const float* rot  = (const float*)Pp[1];
    const float* ck   = (const float*)Pp[3];
    const float* cv   = (const float*)Pp[4];
    const float* wqkv = (const float*)Pp[5];
    const float* wo   = (const float*)Pp[6];
    const int*   sp   = (const int*)Pp[7];

    float* qkv  = (float*)d_ws;                       // 32*6144 (fallback only)
    float* qrot = qkv  + (size_t)BB*NQKV;             // 32*32*128
    float* krot = qrot + (size_t)BB*NH*HD;            // 32*8*128
    float* aout = krot + (size_t)BB*NKV*HD;           // 32*4096
    float* attnp= aout + (size_t)BB*NH*HD;            // 256*8*520
    float* part1= attnp + (size_t)BB*NKV*NCH*520;

    const size_t head_bytes = ((size_t)BB*(NQKV + NH*HD + NKV*HD + NH*HD)
                               + (size_t)BB*NKV*NCH*520) * 4;
    const size_t p1_bytes   = (size_t)32*32*NQKV*4;   // KS1=32 slices
    const size_t p2_bytes   = (size_t)32*32*HIDDEN*4; // KS2=32 slices

    if (ws_size >= head_bytes + p1_bytes + p2_bytes) {
        const int KS1 = 32, KS2 = 32;
        float* part2 = part1 + (size_t)KS1*32*NQKV;

        gemm_f32<NQKV><<<dim3(NQKV/256, KS1), 256, 0, stream>>>(x, wqkv, part1, HIDDEN/KS1);
        rope_red<<<dim3(BB, 5), 256, 0, stream>>>(part1, KS1, rot, qrot, krot);
        attn_chunk<<<dim3(BB*NKV, NCH), 256, 0, stream>>>(qrot, krot, part1, KS1, ck, cv, sp, attnp);
        attn_reduce<<<BB*NKV, 512, 0, stream>>>(attnp, sp, aout);
        gemm_f32<HIDDEN><<<dim3(HIDDEN/256, KS2), 256, 0, stream>>>(aout, wo, part2, HIDDEN/KS2);
        reduce_part<HIDDEN><<<(BB*HIDDEN + 255)/256, 256, 0, stream>>>(part2, (float*)d_out, KS2);
    } else {
        // fallback: small-ws path
        size_t per_ks = (size_t)32*(NQKV + HIDDEN) * 4;
        size_t avail = (ws_size > head_bytes) ? ws_size - head_bytes : 0;
        int KS = 1;
        if      (avail >= 8*per_ks) KS = 8;
        else if (avail >= 4*per_ks) KS = 4;
        else if (avail >= 2*per_ks) KS = 2;
        float* part2 = part1 + (size_t)KS*32*NQKV;

        gemm_f32<NQKV><<<dim3(NQKV/256, KS), 256, 0, stream>>>(x, wqkv, part1, HIDDEN/KS);
        reduce_part<NQKV><<<(BB*NQKV + 255)/256, 256, 0, stream>>>(part1, qkv, KS);
        rope_red<<<dim3(BB, 5), 256, 0, stream>>>(part1, KS, rot, qrot, krot);
        attn_kernel<<<BB*NKV, 512, 0, stream>>>(qrot, krot, qkv, ck, cv, sp, aout);
        gemm_f32<HIDDEN><<<dim3(HIDDEN/256, KS), 256, 0, stream>>>(aout, wo, part2, HIDDEN/KS);
        reduce_part<HIDDEN><<<(BB*HIDDEN + 255)/256, 256, 0, stream>>>(part2, (float*)d_out, KS);
    }
}

// Round 13
// 302.016 us; speedup vs baseline: 1.0218x; 1.0218x over previous
//
#include <hip/hip_runtime.h>
#include <hip/hip_bf16.h>
#include <stdint.h>

#define SW 4096
#define NH 32
#define NKV 8
#define GROUP 4
#define HD 128
#define HIDDEN 4096
#define BB 32
#define NQKV ((NH + 2*NKV)*HD)   // 6144
#define CH 512                   // positions per attention chunk
#define CHP (CH + 4)             // padded row for scl
#define NCH 8                    // max chunks (SW/CH)

// ---------------- LDS-staged K-split GEMM (round-11 proven body) ----------------
template<int NW>
__global__ __launch_bounds__(256)
void gemm_f32(const float* __restrict__ A, const float* __restrict__ W,
              float* __restrict__ part, int kchunk) {
    const int n0 = blockIdx.x * 256;
    const int K0 = blockIdx.y * kchunk;
    const int t = threadIdx.x;
    const int tm = t >> 6;
    const int tn = t & 63;
    __shared__ float a_lds[32*36];
    __shared__ float w_lds[32*256];

    float acc[8][4];
    #pragma unroll
    for (int i = 0; i < 8; ++i)
        #pragma unroll
        for (int j = 0; j < 4; ++j) acc[i][j] = 0.f;

    for (int ks = 0; ks < kchunk; ks += 32) {
        {
            int m = t & 31, kl = t >> 5;
            #pragma unroll
            for (int i = 0; i < 4; ++i) {
                int k = kl + i*8;
                a_lds[k*36 + m] = A[(size_t)m*HIDDEN + K0 + ks + k];
            }
        }
        {
            #pragma unroll
            for (int i = 0; i < 8; ++i) {
                int j = t + i*256;
                int k = j >> 6, c = j & 63;
                const float4* src = (const float4*)(W + (size_t)(K0 + ks + k)*NW + n0);
                *(float4*)&w_lds[k*256 + c*4] = src[c];
            }
        }
        __syncthreads();
        #pragma unroll 8
        for (int k = 0; k < 32; ++k) {
            float4 a0 = *(const float4*)&a_lds[k*36 + tm*8];
            float4 a1 = *(const float4*)&a_lds[k*36 + tm*8 + 4];
            float4 w  = *(const float4*)&w_lds[k*256 + tn*4];
            float am[8] = {a0.x,a0.y,a0.z,a0.w,a1.x,a1.y,a1.z,a1.w};
            #pragma unroll
            for (int mi = 0; mi < 8; ++mi) {
                acc[mi][0] += am[mi]*w.x;
                acc[mi][1] += am[mi]*w.y;
                acc[mi][2] += am[mi]*w.z;
                acc[mi][3] += am[mi]*w.w;
            }
        }
        __syncthreads();
    }
    float* dst = part + (size_t)blockIdx.y*32*NW;
    #pragma unroll
    for (int mi = 0; mi < 8; ++mi) {
        int m = tm*8 + mi;
        float4 v = make_float4(acc[mi][0], acc[mi][1], acc[mi][2], acc[mi][3]);
        *(float4*)&dst[(size_t)m*NW + n0 + tn*4] = v;
    }
}

template<int NW>
__global__ __launch_bounds__(256)
void reduce_part(const float* __restrict__ part, float* __restrict__ out, int ksplit) {
    int idx = blockIdx.x*256 + threadIdx.x;
    if (idx >= 32*NW) return;
    float s = 0.f;
    for (int i = 0; i < ksplit; ++i) s += part[(size_t)i*32*NW + idx];
    out[idx] = s;
}

// ---------------- RoPE fused with K-split reduction of part1 ----------------
__global__ __launch_bounds__(256)
void rope_red(const float* __restrict__ part1, int KS, const float* __restrict__ rot,
              float* __restrict__ qrot, float* __restrict__ krot) {
    const int b = blockIdx.x;
    const int hbase = blockIdx.y * 8;
    const int t = threadIdx.x;
    __shared__ float Rl[64 * HD];
    __shared__ float qin[8 * HD];
    {
        const float* qsrc = part1 + (size_t)b * NQKV + (size_t)hbase * HD;
        float4 a = make_float4(0.f, 0.f, 0.f, 0.f);
        for (int i = 0; i < KS; ++i) {
            float4 v = ((const float4*)(qsrc + (size_t)i * 32 * NQKV))[t];
            a.x += v.x; a.y += v.y; a.z += v.z; a.w += v.w;
        }
        ((float4*)qin)[t] = a;
    }

    float acc[4] = {0.f, 0.f, 0.f, 0.f};
    for (int pass = 0; pass < 2; ++pass) {
        const float4* rsrc = (const float4*)(rot + (size_t)b * HD * HD + pass * 64 * HD);
        #pragma unroll
        for (int i = 0; i < 8; ++i) {
            int j = t + i * 256;
            ((float4*)Rl)[j] = rsrc[j];
        }
        __syncthreads();
        #pragma unroll
        for (int i = 0; i < 4; ++i) {
            int o = t + i * 256;
            int h = o >> 7, e = o & 127;
            float s = 0.f;
            for (int d = 0; d < 64; ++d) s += qin[h * HD + pass * 64 + d] * Rl[d * HD + e];
            acc[i] += s;
        }
        __syncthreads();
    }
    #pragma unroll
    for (int i = 0; i < 4; ++i) {
        int o = t + i * 256;
        int h = o >> 7, e = o & 127;
        int hh = hbase + h;
        if (hh < NH) qrot[((size_t)b * NH + hh) * HD + e] = acc[i];
        else         krot[((size_t)b * NKV + (hh - NH)) * HD + e] = acc[i];
    }
}

__device__ __forceinline__ void window_of(int sp, int& lo, int& hi, int& cur) {
    cur = ((sp % SW) + SW) % SW;
    if (sp < SW) { lo = 0; hi = sp + 1; } else { lo = cur; hi = SW - cur; }
}

// ---------------- flash-decode attention v3: q in registers, nc-bounded loops ----------------
// block = (b*8+kv, chunk of 512), 256 threads.
// partial layout per (bkv, c): o[4*128], m[4], l[4]  => 520 floats
__global__ __launch_bounds__(256)
void attn_chunk(const float* __restrict__ qrot, const float* __restrict__ krot,
                const float* __restrict__ part1, int KS,
                const float* __restrict__ ck, const float* __restrict__ cv,
                const int* __restrict__ spp, float* __restrict__ attnp) {
    const int bkv = blockIdx.x;
    const int b = bkv >> 3, kv = bkv & 7;
    const int c = blockIdx.y;
    const int t = threadIdx.x;
    int lo, hi, cur;
    window_of(spp[0], lo, hi, cur);
    const int n = hi - lo;
    const int base0 = c * CH;
    if (base0 >= n) return;                       // block-uniform exit
    const int nc = (n - base0 < CH) ? (n - base0) : CH;
    const size_t kvoff = (size_t)(b * NKV + kv) * SW * HD;
    const float scale = 0.08838834764831845f;     // 1/sqrt(128)

    __shared__ float q_lds[GROUP * HD];           // 2KB
    __shared__ float scl[GROUP * CHP];            // 8.25KB scores -> probs (padded)
    __shared__ float vnew[HD];                    // 0.5KB
    __shared__ float mg[GROUP], lg[GROUP];
    __shared__ float pp[4][GROUP][HD];            // 8KB

    {
        const size_t qoff = ((size_t)b * NH + kv * GROUP) * HD;
        q_lds[t]       = qrot[qoff + t];
        q_lds[256 + t] = qrot[qoff + 256 + t];
    }
    if (t < HD) {   // vnew = sum over K-split slices (L2-resident)
        const float* vsrc = part1 + (size_t)b * NQKV + (size_t)(NH + NKV) * HD + kv * HD + t;
        float s = 0.f;
        for (int i = 0; i < KS; ++i) s += vsrc[(size_t)i * 32 * NQKV];
        vnew[t] = s;
    }
    __syncthreads();

    const int iters = (nc + 31) >> 5;             // score iterations actually needed

    // ---- scores: 8 lanes per position; q hoisted to registers (zero LDS in loop) ----
    {
        const int dsl  = t & 7;                   // d-slice: d = j*32 + dsl*4
        const int posw = (t >> 3) & 7;            // position within wave's 8
        const int w    = t >> 6;                  // wave id
        float4 qreg[GROUP][4];
        #pragma unroll
        for (int g = 0; g < GROUP; ++g)
            #pragma unroll
            for (int j = 0; j < 4; ++j)
                qreg[g][j] = *(const float4*)&q_lds[g*HD + j*32 + dsl*4];

        const float* krow = krot + ((size_t)b * NKV + kv) * HD;
        #pragma unroll 1
        for (int it = 0; it < iters; ++it) {      // 32 positions/block each
            const int r = it*32 + w*8 + posw;
            const bool valid = (r < nc);
            float s0 = 0.f, s1 = 0.f, s2 = 0.f, s3 = 0.f;
            if (valid) {
                const int p = lo + base0 + r;
                const float* kbase = (p == cur) ? krow : (ck + kvoff + (size_t)p * HD);
                #pragma unroll
                for (int j = 0; j < 4; ++j) {
                    float4 kk = *(const float4*)&kbase[j*32 + dsl*4];
                    s0 += kk.x*qreg[0][j].x + kk.y*qreg[0][j].y + kk.z*qreg[0][j].z + kk.w*qreg[0][j].w;
                    s1 += kk.x*qreg[1][j].x + kk.y*qreg[1][j].y + kk.z*qreg[1][j].z + kk.w*qreg[1][j].w;
                    s2 += kk.x*qreg[2][j].x + kk.y*qreg[2][j].y + kk.z*qreg[2][j].z + kk.w*qreg[2][j].w;
                    s3 += kk.x*qreg[3][j].x + kk.y*qreg[3][j].y + kk.z*qreg[3][j].z + kk.w*qreg[3][j].w;
                }
            }
            // reduce across the 8 d-slice lanes
            s0 += __shfl_xor(s0, 1); s0 += __shfl_xor(s0, 2); s0 += __shfl_xor(s0, 4);
            s1 += __shfl_xor(s1, 1); s1 += __shfl_xor(s1, 2); s1 += __shfl_xor(s1, 4);
            s2 += __shfl_xor(s2, 1); s2 += __shfl_xor(s2, 2); s2 += __shfl_xor(s2, 4);
            s3 += __shfl_xor(s3, 1); s3 += __shfl_xor(s3, 2); s3 += __shfl_xor(s3, 4);
            float sg = (dsl == 0) ? s0 : (dsl == 1) ? s1 : (dsl == 2) ? s2 : s3;
            if (dsl < GROUP)
                scl[dsl * CHP + r] = valid ? sg * scale : -3.0e38f;
        }
        // prefill tail region not covered by the bounded loop
        for (int r = (iters << 5) + t; r < CH; r += 256)
            #pragma unroll
            for (int g = 0; g < GROUP; ++g) scl[g*CHP + r] = -3.0e38f;
    }
    __syncthreads();

    // ---- softmax partials: wave w reduces group w ----
    {
        const int w = t >> 6, l = t & 63;
        float v[8];
        float m = -3.0e38f;
        #pragma unroll
        for (int j = 0; j < 8; ++j) {
            v[j] = scl[w*CHP + l + 64*j];
            m = fmaxf(m, v[j]);
        }
        #pragma unroll
        for (int off = 32; off; off >>= 1) m = fmaxf(m, __shfl_xor(m, off));
        float ss = 0.f;
        #pragma unroll
        for (int j = 0; j < 8; ++j) {
            float e = __expf(v[j] - m);
            scl[w*CHP + l + 64*j] = e;
            ss += e;
        }
        #pragma unroll
        for (int off = 32; off; off >>= 1) ss += __shfl_xor(ss, off);
        if (l == 0) { mg[w] = m; lg[w] = ss; }
    }
    __syncthreads();

    // ---- partial PV: wave rg owns rows [rg*128, +128) bounded by nc; b128 prob broadcasts ----
    {
        const int d2 = (t & 63) * 2, rg = t >> 6;
        const int r0 = rg * (CH/4);
        const int nrows = (nc > r0) ? ((nc - r0 < CH/4) ? nc - r0 : CH/4) : 0;
        const int imax = (nrows + 3) >> 2;
        const float2 vn2 = *(const float2*)&vnew[d2];
        float a0[GROUP], a1[GROUP];
        #pragma unroll
        for (int g = 0; g < GROUP; ++g) { a0[g] = 0.f; a1[g] = 0.f; }
        #pragma unroll 1
        for (int i = 0; i < imax; ++i) {          // 4 rows each
            const int r = r0 + i*4;
            float4 pr[GROUP];
            #pragma unroll
            for (int g = 0; g < GROUP; ++g)
                pr[g] = *(const float4*)&scl[g*CHP + r];
            #pragma unroll
            for (int k = 0; k < 4; ++k) {
                const int rr = r + k;
                const int p = lo + base0 + rr;
                float2 v;
                if (rr >= nc)      v = make_float2(0.f, 0.f);
                else if (p == cur) v = vn2;
                else               v = *(const float2*)&cv[kvoff + (size_t)p * HD + d2];
                const float p0 = (k == 0) ? pr[0].x : (k == 1) ? pr[0].y : (k == 2) ? pr[0].z : pr[0].w;
                const float p1 = (k == 0) ? pr[1].x : (k == 1) ? pr[1].y : (k == 2) ? pr[1].z : pr[1].w;
                const float p2 = (k == 0) ? pr[2].x : (k == 1) ? pr[2].y : (k == 2) ? pr[2].z : pr[2].w;
                const float p3 = (k == 0) ? pr[3].x : (k == 1) ? pr[3].y : (k == 2) ? pr[3].z : pr[3].w;
                a0[0] += p0 * v.x; a1[0] += p0 * v.y;
                a0[1] += p1 * v.x; a1[1] += p1 * v.y;
                a0[2] += p2 * v.x; a1[2] += p2 * v.y;
                a0[3] += p3 * v.x; a1[3] += p3 * v.y;
            }
        }
        #pragma unroll
        for (int g = 0; g < GROUP; ++g) {
            pp[rg][g][d2]     = a0[g];
            pp[rg][g][d2 + 1] = a1[g];
        }
    }
    __syncthreads();
    {
        float* op = attnp + ((size_t)bkv * NCH + c) * 520;
        #pragma unroll
        for (int j = 0; j < 2; ++j) {
            int v = t + 256*j;
            int g = v >> 7, d = v & 127;
            op[g * HD + d] = pp[0][g][d] + pp[1][g][d] + pp[2][g][d] + pp[3][g][d];
        }
        if (t < GROUP) {
            op[512 + t] = mg[t];
            op[516 + t] = lg[t];
        }
    }
}

// merge chunk partials: out = sum_c exp(m_c - M) o_c / sum_c exp(m_c - M) l_c
__global__ __launch_bounds__(512)
void attn_reduce(const float* __restrict__ attnp, const int* __restrict__ spp,
                 float* __restrict__ aout) {
    const int bkv = blockIdx.x;
    const int b = bkv >> 3, kv = bkv & 7;
    const int g = threadIdx.x >> 7, d = threadIdx.x & 127;
    int lo, hi, cur;
    window_of(spp[0], lo, hi, cur);
    const int n = hi - lo;
    const int nch = (n + CH - 1) / CH;
    float M = -3.0e38f;
    for (int c = 0; c < nch; ++c)
        M = fmaxf(M, attnp[((size_t)bkv * NCH + c) * 520 + 512 + g]);
    float L = 0.f, O = 0.f;
    for (int c = 0; c < nch; ++c) {
        const float* op = attnp + ((size_t)bkv * NCH + c) * 520;
        float w = __expf(op[512 + g] - M);
        L += w * op[516 + g];
        O += w * op[g * HD + d];
    }
    aout[(size_t)b * NH * HD + (size_t)(kv * GROUP + g) * HD + d] = O / L;
}

// ---------------- fallback single-block attention (known-good round-6 path) ----------------
__global__ __launch_bounds__(512)
void attn_kernel(const float* __restrict__ qrot, const float* __restrict__ krot,
                 const float* __restrict__ qkv,
                 const float* __restrict__ ck, const float* __restrict__ cv,
                 const int* __restrict__ spp, float* __restrict__ aout) {
    const int b = blockIdx.x >> 3, kv = blockIdx.x & 7;
    const int t = threadIdx.x;
    int lo, hi, cur;
    window_of(spp[0], lo, hi, cur);
    const int n = hi - lo;
    const size_t kvoff = (size_t)(b * NKV + kv) * SW * HD;
    const float scale = 0.08838834764831845f;

    __shared__ float sc[GROUP * 2304];
    __shared__ float q_lds[GROUP * HD];
    __shared__ float redb[512];
    __shared__ float ssum_s[GROUP];

    q_lds[t] = qrot[((size_t)b * NH + kv * GROUP) * HD + t];
    __syncthreads();

    for (int i = t; i < n; i += 512) {
        int p = lo + i;
        float s[GROUP] = {0.f, 0.f, 0.f, 0.f};
        if (p == cur) {
            const float* kr = krot + ((size_t)b * NKV + kv) * HD;
            for (int d = 0; d < HD; ++d) {
                float kd = kr[d];
                #pragma unroll
                for (int g = 0; g < GROUP; ++g) s[g] += kd * q_lds[g * HD + d];
            }
        } else {
            const float* kp = ck + kvoff + (size_t)p * HD;
            for (int c = 0; c < 32; ++c) {
                float4 kk = ((const float4*)kp)[c];
                #pragma unroll
                for (int g = 0; g < GROUP; ++g)
                    s[g] += kk.x * q_lds[g * HD + c * 4] + kk.y * q_lds[g * HD + c * 4 + 1]
                          + kk.z * q_lds[g * HD + c * 4 + 2] + kk.w * q_lds[g * HD + c * 4 + 3];
            }
        }
        #pragma unroll
        for (int g = 0; g < GROUP; ++g)
            sc[g * 2304 + i] = s[g] * scale;
    }
    __syncthreads();

    for (int g = 0; g < GROUP; ++g) {
        float m = -3.0e38f;
        for (int i = t; i < n; i += 512) m = fmaxf(m, sc[g * 2304 + i]);
        redb[t] = m;
        __syncthreads();
        for (int w = 256; w > 0; w >>= 1) {
            if (t < w) redb[t] = fmaxf(redb[t], redb[t + w]);
            __syncthreads();
        }
        float mx = redb[0];
        __syncthreads();
        float s = 0.f;
        for (int i = t; i < n; i += 512) {
            float e = __expf(sc[g * 2304 + i] - mx);
            sc[g * 2304 + i] = e;
            s += e;
        }
        redb[t] = s;
        __syncthreads();
        for (int w = 256; w > 0; w >>= 1) {
            if (t < w) redb[t] += redb[t + w];
            __syncthreads();
        }
        if (t == 0) ssum_s[g] = redb[0];
        __syncthreads();
    }

    {
        const int g = t >> 7, d = t & 127;
        const float vn = qkv[(size_t)b * NQKV + (size_t)(NH + NKV) * HD + kv * HD + d];
        float acc = 0.f;
        for (int r = 0; r < n; ++r) {
            int p = lo + r;
            float v = (p == cur) ? vn : cv[kvoff + (size_t)p * HD + d];
            acc += sc[g * 2304 + r] * v;
        }
        aout[(size_t)b * NH * HD + (size_t)(kv * GROUP + g) * HD + d] = acc / ssum_s[g];
    }
}

extern "C" void kernel_launch(void* const* d_in, const int* in_sizes, int n_in,
                              void* d_out, int out_size, void* d_ws, size_t ws_size,
                              hipStream_t stream) {
    (void)out_size;
    static const long long CS[8] = {131072LL, 524288LL, 4194304LL, 134217728LL,
                                    134217728LL, 25165824LL, 16777216LL, 1LL};
    const void* Pp[8];
    bool canonical = (n_in == 8);
    if (canonical)
        for (int i = 0; i < 8; ++i)
            if ((long long)in_sizes[i] != CS[i]) { canonical = false; break; }
    if (canonical) {
        for (int i = 0; i < 8; ++i) Pp[i] = d_in[i];
    } else {
        bool used[64] = {false};
        for (int j = 0; j < 8; ++j) {
            Pp[j] = d_in[0];
            for (int i = 0; i < n_in && i < 64; ++i)
                if (!used[i] && (long long)in_sizes[i] == CS[j]) { used[i] = true; Pp[j] = d_in[i]; break; }
        }
    }

    const float* x    = (const float*)Pp[0];
    const float* rot  = (const float*)Pp[1];
    const float* ck   = (const float*)Pp[3];
    const float* cv   = (const float*)Pp[4];
    const float* wqkv = (const float*)Pp[5];
    const float* wo   = (const float*)Pp[6];
    const int*   sp   = (const int*)Pp[7];

    float* qkv  = (float*)d_ws;                       // 32*6144 (fallback only)
    float* qrot = qkv  + (size_t)BB*NQKV;             // 32*32*128
    float* krot = qrot + (size_t)BB*NH*HD;            // 32*8*128
    float* aout = krot + (size_t)BB*NKV*HD;           // 32*4096
    float* attnp= aout + (size_t)BB*NH*HD;            // 256*8*520
    float* part1= attnp + (size_t)BB*NKV*NCH*520;

    const size_t head_bytes = ((size_t)BB*(NQKV + NH*HD + NKV*HD + NH*HD)
                               + (size_t)BB*NKV*NCH*520) * 4;
    const size_t p1_bytes   = (size_t)16*32*NQKV*4;   // KS1=16 slices
    const size_t p2_bytes   = (size_t)32*32*HIDDEN*4; // KS2=32 slices

    if (ws_size >= head_bytes + p1_bytes + p2_bytes) {
        const int KS1 = 16, KS2 = 32;
        float* part2 = part1 + (size_t)KS1*32*NQKV;

        gemm_f32<NQKV><<<dim3(NQKV/256, KS1), 256, 0, stream>>>(x, wqkv, part1, HIDDEN/KS1);
        rope_red<<<dim3(BB, 5), 256, 0, stream>>>(part1, KS1, rot, qrot, krot);
        attn_chunk<<<dim3(BB*NKV, NCH), 256, 0, stream>>>(qrot, krot, part1, KS1, ck, cv, sp, attnp);
        attn_reduce<<<BB*NKV, 512, 0, stream>>>(attnp, sp, aout);
        gemm_f32<HIDDEN><<<dim3(HIDDEN/256, KS2), 256, 0, stream>>>(aout, wo, part2, HIDDEN/KS2);
        reduce_part<HIDDEN><<<(BB*HIDDEN + 255)/256, 256, 0, stream>>>(part2, (float*)d_out, KS2);
    } else {
        // fallback: small-ws path
        size_t per_ks = (size_t)32*(NQKV + HIDDEN) * 4;
        size_t avail = (ws_size > head_bytes) ? ws_size - head_bytes : 0;
        int KS = 1;
        if      (avail >= 8*per_ks) KS = 8;
        else if (avail >= 4*per_ks) KS = 4;
        else if (avail >= 2*per_ks) KS = 2;
        float* part2 = part1 + (size_t)KS*32*NQKV;

        gemm_f32<NQKV><<<dim3(NQKV/256, KS), 256, 0, stream>>>(x, wqkv, part1, HIDDEN/KS);
        reduce_part<NQKV><<<(BB*NQKV + 255)/256, 256, 0, stream>>>(part1, qkv, KS);
        rope_red<<<dim3(BB, 5), 256, 0, stream>>>(part1, KS, rot, qrot, krot);
        attn_kernel<<<BB*NKV, 512, 0, stream>>>(qrot, krot, qkv, ck, cv, sp, aout);
        gemm_f32<HIDDEN><<<dim3(HIDDEN/256, KS), 256, 0, stream>>>(aout, wo, part2, HIDDEN/KS);
        reduce_part<HIDDEN><<<(BB*HIDDEN + 255)/256, 256, 0, stream>>>(part2, (float*)d_out, KS);
    }
}

// Round 14
// 238.424 us; speedup vs baseline: 1.2943x; 1.2667x over previous
//
#include <hip/hip_runtime.h>
#include <hip/hip_bf16.h>
#include <stdint.h>

#define SW 4096
#define NH 32
#define NKV 8
#define GROUP 4
#define HD 128
#define HIDDEN 4096
#define BB 32
#define NQKV ((NH + 2*NKV)*HD)   // 6144
#define CH 512                   // positions per attention chunk
#define CHP (CH + 4)             // padded row for scl
#define NCH 8                    // max chunks (SW/CH)

// ---------------- LDS-staged K-split GEMM (round-11 proven body) ----------------
template<int NW>
__global__ __launch_bounds__(256)
void gemm_f32(const float* __restrict__ A, const float* __restrict__ W,
              float* __restrict__ part, int kchunk) {
    const int n0 = blockIdx.x * 256;
    const int K0 = blockIdx.y * kchunk;
    const int t = threadIdx.x;
    const int tm = t >> 6;
    const int tn = t & 63;
    __shared__ float a_lds[32*36];
    __shared__ float w_lds[32*256];

    float acc[8][4];
    #pragma unroll
    for (int i = 0; i < 8; ++i)
        #pragma unroll
        for (int j = 0; j < 4; ++j) acc[i][j] = 0.f;

    for (int ks = 0; ks < kchunk; ks += 32) {
        {
            int m = t & 31, kl = t >> 5;
            #pragma unroll
            for (int i = 0; i < 4; ++i) {
                int k = kl + i*8;
                a_lds[k*36 + m] = A[(size_t)m*HIDDEN + K0 + ks + k];
            }
        }
        {
            #pragma unroll
            for (int i = 0; i < 8; ++i) {
                int j = t + i*256;
                int k = j >> 6, c = j & 63;
                const float4* src = (const float4*)(W + (size_t)(K0 + ks + k)*NW + n0);
                *(float4*)&w_lds[k*256 + c*4] = src[c];
            }
        }
        __syncthreads();
        #pragma unroll 8
        for (int k = 0; k < 32; ++k) {
            float4 a0 = *(const float4*)&a_lds[k*36 + tm*8];
            float4 a1 = *(const float4*)&a_lds[k*36 + tm*8 + 4];
            float4 w  = *(const float4*)&w_lds[k*256 + tn*4];
            float am[8] = {a0.x,a0.y,a0.z,a0.w,a1.x,a1.y,a1.z,a1.w};
            #pragma unroll
            for (int mi = 0; mi < 8; ++mi) {
                acc[mi][0] += am[mi]*w.x;
                acc[mi][1] += am[mi]*w.y;
                acc[mi][2] += am[mi]*w.z;
                acc[mi][3] += am[mi]*w.w;
            }
        }
        __syncthreads();
    }
    float* dst = part + (size_t)blockIdx.y*32*NW;
    #pragma unroll
    for (int mi = 0; mi < 8; ++mi) {
        int m = tm*8 + mi;
        float4 v = make_float4(acc[mi][0], acc[mi][1], acc[mi][2], acc[mi][3]);
        *(float4*)&dst[(size_t)m*NW + n0 + tn*4] = v;
    }
}

template<int NW>
__global__ __launch_bounds__(256)
void reduce_part(const float* __restrict__ part, float* __restrict__ out, int ksplit) {
    int idx = blockIdx.x*256 + threadIdx.x;
    if (idx >= 32*NW) return;
    float s = 0.f;
    for (int i = 0; i < ksplit; ++i) s += part[(size_t)i*32*NW + idx];
    out[idx] = s;
}

// ---------------- RoPE fused with K-split reduction of part1 ----------------
__global__ __launch_bounds__(256)
void rope_red(const float* __restrict__ part1, int KS, const float* __restrict__ rot,
              float* __restrict__ qrot, float* __restrict__ krot) {
    const int b = blockIdx.x;
    const int hbase = blockIdx.y * 8;
    const int t = threadIdx.x;
    __shared__ float Rl[64 * HD];
    __shared__ float qin[8 * HD];
    {
        const float* qsrc = part1 + (size_t)b * NQKV + (size_t)hbase * HD;
        float4 a = make_float4(0.f, 0.f, 0.f, 0.f);
        for (int i = 0; i < KS; ++i) {
            float4 v = ((const float4*)(qsrc + (size_t)i * 32 * NQKV))[t];
            a.x += v.x; a.y += v.y; a.z += v.z; a.w += v.w;
        }
        ((float4*)qin)[t] = a;
    }

    float acc[4] = {0.f, 0.f, 0.f, 0.f};
    for (int pass = 0; pass < 2; ++pass) {
        const float4* rsrc = (const float4*)(rot + (size_t)b * HD * HD + pass * 64 * HD);
        #pragma unroll
        for (int i = 0; i < 8; ++i) {
            int j = t + i * 256;
            ((float4*)Rl)[j] = rsrc[j];
        }
        __syncthreads();
        #pragma unroll
        for (int i = 0; i < 4; ++i) {
            int o = t + i * 256;
            int h = o >> 7, e = o & 127;
            float s = 0.f;
            for (int d = 0; d < 64; ++d) s += qin[h * HD + pass * 64 + d] * Rl[d * HD + e];
            acc[i] += s;
        }
        __syncthreads();
    }
    #pragma unroll
    for (int i = 0; i < 4; ++i) {
        int o = t + i * 256;
        int h = o >> 7, e = o & 127;
        int hh = hbase + h;
        if (hh < NH) qrot[((size_t)b * NH + hh) * HD + e] = acc[i];
        else         krot[((size_t)b * NKV + (hh - NH)) * HD + e] = acc[i];
    }
}

__device__ __forceinline__ void window_of(int sp, int& lo, int& hi, int& cur) {
    cur = ((sp % SW) + SW) % SW;
    if (sp < SW) { lo = 0; hi = sp + 1; } else { lo = cur; hi = SW - cur; }
}

// ---------------- flash-decode attention v2 (round-11 body): q in registers, ----------------
// compile-time loop bounds (runtime nc-bounds measured +65us regression, R12/R13).
// block = (b*8+kv, chunk of 512), 256 threads.
// partial layout per (bkv, c): o[4*128], m[4], l[4]  => 520 floats
__global__ __launch_bounds__(256)
void attn_chunk(const float* __restrict__ qrot, const float* __restrict__ krot,
                const float* __restrict__ part1, int KS,
                const float* __restrict__ ck, const float* __restrict__ cv,
                const int* __restrict__ spp, float* __restrict__ attnp) {
    const int bkv = blockIdx.x;
    const int b = bkv >> 3, kv = bkv & 7;
    const int c = blockIdx.y;
    const int t = threadIdx.x;
    int lo, hi, cur;
    window_of(spp[0], lo, hi, cur);
    const int n = hi - lo;
    const int base0 = c * CH;
    if (base0 >= n) return;                       // block-uniform exit
    const int nc = (n - base0 < CH) ? (n - base0) : CH;
    const size_t kvoff = (size_t)(b * NKV + kv) * SW * HD;
    const float scale = 0.08838834764831845f;     // 1/sqrt(128)

    __shared__ float q_lds[GROUP * HD];           // 2KB
    __shared__ float scl[GROUP * CHP];            // 8.25KB scores -> probs (padded)
    __shared__ float vnew[HD];                    // 0.5KB
    __shared__ float mg[GROUP], lg[GROUP];
    __shared__ float pp[4][GROUP][HD];            // 8KB

    {
        const size_t qoff = ((size_t)b * NH + kv * GROUP) * HD;
        q_lds[t]       = qrot[qoff + t];
        q_lds[256 + t] = qrot[qoff + 256 + t];
    }
    if (t < HD) {   // vnew = sum over K-split slices (L2-resident)
        const float* vsrc = part1 + (size_t)b * NQKV + (size_t)(NH + NKV) * HD + kv * HD + t;
        float s = 0.f;
        for (int i = 0; i < KS; ++i) s += vsrc[(size_t)i * 32 * NQKV];
        vnew[t] = s;
    }
    __syncthreads();

    // ---- scores: 8 lanes per position; q hoisted to registers (zero LDS in loop) ----
    {
        const int dsl  = t & 7;                   // d-slice: d = j*32 + dsl*4
        const int posw = (t >> 3) & 7;            // position within wave's 8
        const int w    = t >> 6;                  // wave id
        float4 qreg[GROUP][4];
        #pragma unroll
        for (int g = 0; g < GROUP; ++g)
            #pragma unroll
            for (int j = 0; j < 4; ++j)
                qreg[g][j] = *(const float4*)&q_lds[g*HD + j*32 + dsl*4];

        const float* krow = krot + ((size_t)b * NKV + kv) * HD;
        #pragma unroll 1
        for (int it = 0; it < CH/32; ++it) {      // 16 iters, 32 positions/block each
            const int r = it*32 + w*8 + posw;
            const bool valid = (r < nc);
            float s0 = 0.f, s1 = 0.f, s2 = 0.f, s3 = 0.f;
            if (valid) {
                const int p = lo + base0 + r;
                const float* kbase = (p == cur) ? krow : (ck + kvoff + (size_t)p * HD);
                #pragma unroll
                for (int j = 0; j < 4; ++j) {
                    float4 kk = *(const float4*)&kbase[j*32 + dsl*4];
                    s0 += kk.x*qreg[0][j].x + kk.y*qreg[0][j].y + kk.z*qreg[0][j].z + kk.w*qreg[0][j].w;
                    s1 += kk.x*qreg[1][j].x + kk.y*qreg[1][j].y + kk.z*qreg[1][j].z + kk.w*qreg[1][j].w;
                    s2 += kk.x*qreg[2][j].x + kk.y*qreg[2][j].y + kk.z*qreg[2][j].z + kk.w*qreg[2][j].w;
                    s3 += kk.x*qreg[3][j].x + kk.y*qreg[3][j].y + kk.z*qreg[3][j].z + kk.w*qreg[3][j].w;
                }
            }
            // reduce across the 8 d-slice lanes
            s0 += __shfl_xor(s0, 1); s0 += __shfl_xor(s0, 2); s0 += __shfl_xor(s0, 4);
            s1 += __shfl_xor(s1, 1); s1 += __shfl_xor(s1, 2); s1 += __shfl_xor(s1, 4);
            s2 += __shfl_xor(s2, 1); s2 += __shfl_xor(s2, 2); s2 += __shfl_xor(s2, 4);
            s3 += __shfl_xor(s3, 1); s3 += __shfl_xor(s3, 2); s3 += __shfl_xor(s3, 4);
            float sg = (dsl == 0) ? s0 : (dsl == 1) ? s1 : (dsl == 2) ? s2 : s3;
            if (dsl < GROUP)
                scl[dsl * CHP + r] = valid ? sg * scale : -3.0e38f;
        }
    }
    __syncthreads();

    // ---- softmax partials: wave w reduces group w ----
    {
        const int w = t >> 6, l = t & 63;
        float v[8];
        float m = -3.0e38f;
        #pragma unroll
        for (int j = 0; j < 8; ++j) {
            v[j] = scl[w*CHP + l + 64*j];
            m = fmaxf(m, v[j]);
        }
        #pragma unroll
        for (int off = 32; off; off >>= 1) m = fmaxf(m, __shfl_xor(m, off));
        float ss = 0.f;
        #pragma unroll
        for (int j = 0; j < 8; ++j) {
            float e = __expf(v[j] - m);
            scl[w*CHP + l + 64*j] = e;
            ss += e;
        }
        #pragma unroll
        for (int off = 32; off; off >>= 1) ss += __shfl_xor(ss, off);
        if (l == 0) { mg[w] = m; lg[w] = ss; }
    }
    __syncthreads();

    // ---- partial PV: wave rg owns contiguous rows [rg*128, +128); probs via b128 broadcast ----
    {
        const int d2 = (t & 63) * 2, rg = t >> 6;
        const int r0 = rg * (CH/4);
        const float2 vn2 = *(const float2*)&vnew[d2];
        float a0[GROUP], a1[GROUP];
        #pragma unroll
        for (int g = 0; g < GROUP; ++g) { a0[g] = 0.f; a1[g] = 0.f; }
        #pragma unroll 1
        for (int i = 0; i < CH/16; ++i) {         // 32 iters, 4 rows each
            const int r = r0 + i*4;
            float4 pr[GROUP];
            #pragma unroll
            for (int g = 0; g < GROUP; ++g)
                pr[g] = *(const float4*)&scl[g*CHP + r];
            #pragma unroll
            for (int k = 0; k < 4; ++k) {
                const int rr = r + k;
                const int p = lo + base0 + rr;
                float2 v;
                if (rr >= nc)      v = make_float2(0.f, 0.f);
                else if (p == cur) v = vn2;
                else               v = *(const float2*)&cv[kvoff + (size_t)p * HD + d2];
                const float p0 = (k == 0) ? pr[0].x : (k == 1) ? pr[0].y : (k == 2) ? pr[0].z : pr[0].w;
                const float p1 = (k == 0) ? pr[1].x : (k == 1) ? pr[1].y : (k == 2) ? pr[1].z : pr[1].w;
                const float p2 = (k == 0) ? pr[2].x : (k == 1) ? pr[2].y : (k == 2) ? pr[2].z : pr[2].w;
                const float p3 = (k == 0) ? pr[3].x : (k == 1) ? pr[3].y : (k == 2) ? pr[3].z : pr[3].w;
                a0[0] += p0 * v.x; a1[0] += p0 * v.y;
                a0[1] += p1 * v.x; a1[1] += p1 * v.y;
                a0[2] += p2 * v.x; a1[2] += p2 * v.y;
                a0[3] += p3 * v.x; a1[3] += p3 * v.y;
            }
        }
        #pragma unroll
        for (int g = 0; g < GROUP; ++g) {
            pp[rg][g][d2]     = a0[g];
            pp[rg][g][d2 + 1] = a1[g];
        }
    }
    __syncthreads();
    {
        float* op = attnp + ((size_t)bkv * NCH + c) * 520;
        #pragma unroll
        for (int j = 0; j < 2; ++j) {
            int v = t + 256*j;
            int g = v >> 7, d = v & 127;
            op[g * HD + d] = pp[0][g][d] + pp[1][g][d] + pp[2][g][d] + pp[3][g][d];
        }
        if (t < GROUP) {
            op[512 + t] = mg[t];
            op[516 + t] = lg[t];
        }
    }
}

// merge chunk partials: out = sum_c exp(m_c - M) o_c / sum_c exp(m_c - M) l_c
__global__ __launch_bounds__(512)
void attn_reduce(const float* __restrict__ attnp, const int* __restrict__ spp,
                 float* __restrict__ aout) {
    const int bkv = blockIdx.x;
    const int b = bkv >> 3, kv = bkv & 7;
    const int g = threadIdx.x >> 7, d = threadIdx.x & 127;
    int lo, hi, cur;
    window_of(spp[0], lo, hi, cur);
    const int n = hi - lo;
    const int nch = (n + CH - 1) / CH;
    float M = -3.0e38f;
    for (int c = 0; c < nch; ++c)
        M = fmaxf(M, attnp[((size_t)bkv * NCH + c) * 520 + 512 + g]);
    float L = 0.f, O = 0.f;
    for (int c = 0; c < nch; ++c) {
        const float* op = attnp + ((size_t)bkv * NCH + c) * 520;
        float w = __expf(op[512 + g] - M);
        L += w * op[516 + g];
        O += w * op[g * HD + d];
    }
    aout[(size_t)b * NH * HD + (size_t)(kv * GROUP + g) * HD + d] = O / L;
}

// ---------------- fallback single-block attention (known-good round-6 path) ----------------
__global__ __launch_bounds__(512)
void attn_kernel(const float* __restrict__ qrot, const float* __restrict__ krot,
                 const float* __restrict__ qkv,
                 const float* __restrict__ ck, const float* __restrict__ cv,
                 const int* __restrict__ spp, float* __restrict__ aout) {
    const int b = blockIdx.x >> 3, kv = blockIdx.x & 7;
    const int t = threadIdx.x;
    int lo, hi, cur;
    window_of(spp[0], lo, hi, cur);
    const int n = hi - lo;
    const size_t kvoff = (size_t)(b * NKV + kv) * SW * HD;
    const float scale = 0.08838834764831845f;

    __shared__ float sc[GROUP * 2304];
    __shared__ float q_lds[GROUP * HD];
    __shared__ float redb[512];
    __shared__ float ssum_s[GROUP];

    q_lds[t] = qrot[((size_t)b * NH + kv * GROUP) * HD + t];
    __syncthreads();

    for (int i = t; i < n; i += 512) {
        int p = lo + i;
        float s[GROUP] = {0.f, 0.f, 0.f, 0.f};
        if (p == cur) {
            const float* kr = krot + ((size_t)b * NKV + kv) * HD;
            for (int d = 0; d < HD; ++d) {
                float kd = kr[d];
                #pragma unroll
                for (int g = 0; g < GROUP; ++g) s[g] += kd * q_lds[g * HD + d];
            }
        } else {
            const float* kp = ck + kvoff + (size_t)p * HD;
            for (int c = 0; c < 32; ++c) {
                float4 kk = ((const float4*)kp)[c];
                #pragma unroll
                for (int g = 0; g < GROUP; ++g)
                    s[g] += kk.x * q_lds[g * HD + c * 4] + kk.y * q_lds[g * HD + c * 4 + 1]
                          + kk.z * q_lds[g * HD + c * 4 + 2] + kk.w * q_lds[g * HD + c * 4 + 3];
            }
        }
        #pragma unroll
        for (int g = 0; g < GROUP; ++g)
            sc[g * 2304 + i] = s[g] * scale;
    }
    __syncthreads();

    for (int g = 0; g < GROUP; ++g) {
        float m = -3.0e38f;
        for (int i = t; i < n; i += 512) m = fmaxf(m, sc[g * 2304 + i]);
        redb[t] = m;
        __syncthreads();
        for (int w = 256; w > 0; w >>= 1) {
            if (t < w) redb[t] = fmaxf(redb[t], redb[t + w]);
            __syncthreads();
        }
        float mx = redb[0];
        __syncthreads();
        float s = 0.f;
        for (int i = t; i < n; i += 512) {
            float e = __expf(sc[g * 2304 + i] - mx);
            sc[g * 2304 + i] = e;
            s += e;
        }
        redb[t] = s;
        __syncthreads();
        for (int w = 256; w > 0; w >>= 1) {
            if (t < w) redb[t] += redb[t + w];
            __syncthreads();
        }
        if (t == 0) ssum_s[g] = redb[0];
        __syncthreads();
    }

    {
        const int g = t >> 7, d = t & 127;
        const float vn = qkv[(size_t)b * NQKV + (size_t)(NH + NKV) * HD + kv * HD + d];
        float acc = 0.f;
        for (int r = 0; r < n; ++r) {
            int p = lo + r;
            float v = (p == cur) ? vn : cv[kvoff + (size_t)p * HD + d];
            acc += sc[g * 2304 + r] * v;
        }
        aout[(size_t)b * NH * HD + (size_t)(kv * GROUP + g) * HD + d] = acc / ssum_s[g];
    }
}

extern "C" void kernel_launch(void* const* d_in, const int* in_sizes, int n_in,
                              void* d_out, int out_size, void* d_ws, size_t ws_size,
                              hipStream_t stream) {
    (void)out_size;
    static const long long CS[8] = {131072LL, 524288LL, 4194304LL, 134217728LL,
                                    134217728LL, 25165824LL, 16777216LL, 1LL};
    const void* Pp[8];
    bool canonical = (n_in == 8);
    if (canonical)
        for (int i = 0; i < 8; ++i)
            if ((long long)in_sizes[i] != CS[i]) { canonical = false; break; }
    if (canonical) {
        for (int i = 0; i < 8; ++i) Pp[i] = d_in[i];
    } else {
        bool used[64] = {false};
        for (int j = 0; j < 8; ++j) {
            Pp[j] = d_in[0];
            for (int i = 0; i < n_in && i < 64; ++i)
                if (!used[i] && (long long)in_sizes[i] == CS[j]) { used[i] = true; Pp[j] = d_in[i]; break; }
        }
    }

    const float* x    = (const float*)Pp[0];
    const float* rot  = (const float*)Pp[1];
    const float* ck   = (const float*)Pp[3];
    const float* cv   = (const float*)Pp[4];
    const float* wqkv = (const float*)Pp[5];
    const float* wo   = (const float*)Pp[6];
    const int*   sp   = (const int*)Pp[7];

    float* qkv  = (float*)d_ws;                       // 32*6144 (fallback only)
    float* qrot = qkv  + (size_t)BB*NQKV;             // 32*32*128
    float* krot = qrot + (size_t)BB*NH*HD;            // 32*8*128
    float* aout = krot + (size_t)BB*NKV*HD;           // 32*4096
    float* attnp= aout + (size_t)BB*NH*HD;            // 256*8*520
    float* part1= attnp + (size_t)BB*NKV*NCH*520;

    const size_t head_bytes = ((size_t)BB*(NQKV + NH*HD + NKV*HD + NH*HD)
                               + (size_t)BB*NKV*NCH*520) * 4;
    const size_t p1_bytes   = (size_t)16*32*NQKV*4;   // KS1=16 slices
    const size_t p2_bytes   = (size_t)32*32*HIDDEN*4; // KS2=32 slices

    if (ws_size >= head_bytes + p1_bytes + p2_bytes) {
        const int KS1 = 16, KS2 = 32;
        float* part2 = part1 + (size_t)KS1*32*NQKV;

        gemm_f32<NQKV><<<dim3(NQKV/256, KS1), 256, 0, stream>>>(x, wqkv, part1, HIDDEN/KS1);
        rope_red<<<dim3(BB, 5), 256, 0, stream>>>(part1, KS1, rot, qrot, krot);
        attn_chunk<<<dim3(BB*NKV, NCH), 256, 0, stream>>>(qrot, krot, part1, KS1, ck, cv, sp, attnp);
        attn_reduce<<<BB*NKV, 512, 0, stream>>>(attnp, sp, aout);
        gemm_f32<HIDDEN><<<dim3(HIDDEN/256, KS2), 256, 0, stream>>>(aout, wo, part2, HIDDEN/KS2);
        reduce_part<HIDDEN><<<(BB*HIDDEN + 255)/256, 256, 0, stream>>>(part2, (float*)d_out, KS2);
    } else {
        // fallback: small-ws path
        size_t per_ks = (size_t)32*(NQKV + HIDDEN) * 4;
        size_t avail = (ws_size > head_bytes) ? ws_size - head_bytes : 0;
        int KS = 1;
        if      (avail >= 8*per_ks) KS = 8;
        else if (avail >= 4*per_ks) KS = 4;
        else if (avail >= 2*per_ks) KS = 2;
        float* part2 = part1 + (size_t)KS*32*NQKV;

        gemm_f32<NQKV><<<dim3(NQKV/256, KS), 256, 0, stream>>>(x, wqkv, part1, HIDDEN/KS);
        reduce_part<NQKV><<<(BB*NQKV + 255)/256, 256, 0, stream>>>(part1, qkv, KS);
        rope_red<<<dim3(BB, 5), 256, 0, stream>>>(part1, KS, rot, qrot, krot);
        attn_kernel<<<BB*NKV, 512, 0, stream>>>(qrot, krot, qkv, ck, cv, sp, aout);
        gemm_f32<HIDDEN><<<dim3(HIDDEN/256, KS), 256, 0, stream>>>(aout, wo, part2, HIDDEN/KS);
        reduce_part<HIDDEN><<<(BB*HIDDEN + 255)/256, 256, 0, stream>>>(part2, (float*)d_out, KS);
    }
}

// Round 15
// 236.544 us; speedup vs baseline: 1.3046x; 1.0079x over previous
//
#include <hip/hip_runtime.h>
#include <hip/hip_bf16.h>
#include <stdint.h>

#define SW 4096
#define NH 32
#define NKV 8
#define GROUP 4
#define HD 128
#define HIDDEN 4096
#define BB 32
#define NQKV ((NH + 2*NKV)*HD)   // 6144
#define CH 512                   // positions per attention chunk
#define CHP (CH + 4)             // padded row for scl
#define NCH 8                    // max chunks (SW/CH)

// ---------------- LDS-staged K-split GEMM, BN=128 tile (hi-occupancy variant) ----------------
// Same staging/FMA pattern as the proven 256-wide body; tile halved so LDS=20.6KB
// -> ~7 blocks/CU resident (vs 1.5 at 384 blocks/36.6KB), hiding stage latency.
template<int NW>
__global__ __launch_bounds__(256)
void gemm_f32(const float* __restrict__ A, const float* __restrict__ W,
              float* __restrict__ part, int kchunk) {
    const int n0 = blockIdx.x * 128;
    const int K0 = blockIdx.y * kchunk;
    const int t = threadIdx.x;
    const int tm = t >> 5;      // 0..7 -> m base tm*4
    const int tn = t & 31;      // 0..31 -> n = n0 + tn*4
    __shared__ float a_lds[32*36];   // [k][m], stride 36 (144B rows, 16B-aligned)
    __shared__ float w_lds[32*128];  // [k][n] 16KB

    float acc[4][4];
    #pragma unroll
    for (int i = 0; i < 4; ++i)
        #pragma unroll
        for (int j = 0; j < 4; ++j) acc[i][j] = 0.f;

    for (int ks = 0; ks < kchunk; ks += 32) {
        {   // stage A: 32k x 32m (1024 elems, 4/thread)
            int m = t & 31, kl = t >> 5;
            #pragma unroll
            for (int i = 0; i < 4; ++i) {
                int k = kl + i*8;
                a_lds[k*36 + m] = A[(size_t)m*HIDDEN + K0 + ks + k];
            }
        }
        {   // stage W: 32k x 128n = 1024 float4, 4/thread
            #pragma unroll
            for (int i = 0; i < 4; ++i) {
                int j = t + i*256;
                int k = j >> 5, c = j & 31;
                const float4* src = (const float4*)(W + (size_t)(K0 + ks + k)*NW + n0);
                *(float4*)&w_lds[k*128 + c*4] = src[c];
            }
        }
        __syncthreads();
        #pragma unroll 8
        for (int k = 0; k < 32; ++k) {
            float4 a0 = *(const float4*)&a_lds[k*36 + tm*4];
            float4 w  = *(const float4*)&w_lds[k*128 + tn*4];
            float am[4] = {a0.x, a0.y, a0.z, a0.w};
            #pragma unroll
            for (int mi = 0; mi < 4; ++mi) {
                acc[mi][0] += am[mi]*w.x;
                acc[mi][1] += am[mi]*w.y;
                acc[mi][2] += am[mi]*w.z;
                acc[mi][3] += am[mi]*w.w;
            }
        }
        __syncthreads();
    }
    float* dst = part + (size_t)blockIdx.y*32*NW;
    #pragma unroll
    for (int mi = 0; mi < 4; ++mi) {
        int m = tm*4 + mi;
        float4 v = make_float4(acc[mi][0], acc[mi][1], acc[mi][2], acc[mi][3]);
        *(float4*)&dst[(size_t)m*NW + n0 + tn*4] = v;
    }
}

template<int NW>
__global__ __launch_bounds__(256)
void reduce_part(const float* __restrict__ part, float* __restrict__ out, int ksplit) {
    int idx = blockIdx.x*256 + threadIdx.x;
    if (idx >= 32*NW) return;
    float s = 0.f;
    for (int i = 0; i < ksplit; ++i) s += part[(size_t)i*32*NW + idx];
    out[idx] = s;
}

// ---------------- RoPE fused with K-split reduction of part1 ----------------
__global__ __launch_bounds__(256)
void rope_red(const float* __restrict__ part1, int KS, const float* __restrict__ rot,
              float* __restrict__ qrot, float* __restrict__ krot) {
    const int b = blockIdx.x;
    const int hbase = blockIdx.y * 8;
    const int t = threadIdx.x;
    __shared__ float Rl[64 * HD];
    __shared__ float qin[8 * HD];
    {
        const float* qsrc = part1 + (size_t)b * NQKV + (size_t)hbase * HD;
        float4 a = make_float4(0.f, 0.f, 0.f, 0.f);
        for (int i = 0; i < KS; ++i) {
            float4 v = ((const float4*)(qsrc + (size_t)i * 32 * NQKV))[t];
            a.x += v.x; a.y += v.y; a.z += v.z; a.w += v.w;
        }
        ((float4*)qin)[t] = a;
    }

    float acc[4] = {0.f, 0.f, 0.f, 0.f};
    for (int pass = 0; pass < 2; ++pass) {
        const float4* rsrc = (const float4*)(rot + (size_t)b * HD * HD + pass * 64 * HD);
        #pragma unroll
        for (int i = 0; i < 8; ++i) {
            int j = t + i * 256;
            ((float4*)Rl)[j] = rsrc[j];
        }
        __syncthreads();
        #pragma unroll
        for (int i = 0; i < 4; ++i) {
            int o = t + i * 256;
            int h = o >> 7, e = o & 127;
            float s = 0.f;
            for (int d = 0; d < 64; ++d) s += qin[h * HD + pass * 64 + d] * Rl[d * HD + e];
            acc[i] += s;
        }
        __syncthreads();
    }
    #pragma unroll
    for (int i = 0; i < 4; ++i) {
        int o = t + i * 256;
        int h = o >> 7, e = o & 127;
        int hh = hbase + h;
        if (hh < NH) qrot[((size_t)b * NH + hh) * HD + e] = acc[i];
        else         krot[((size_t)b * NKV + (hh - NH)) * HD + e] = acc[i];
    }
}

__device__ __forceinline__ void window_of(int sp, int& lo, int& hi, int& cur) {
    cur = ((sp % SW) + SW) % SW;
    if (sp < SW) { lo = 0; hi = sp + 1; } else { lo = cur; hi = SW - cur; }
}

// ---------------- flash-decode attention v2 (round-11 body): q in registers, ----------------
// compile-time loop bounds (runtime nc-bounds measured +65us regression, R12/R13).
// block = (b*8+kv, chunk of 512), 256 threads.
// partial layout per (bkv, c): o[4*128], m[4], l[4]  => 520 floats
__global__ __launch_bounds__(256)
void attn_chunk(const float* __restrict__ qrot, const float* __restrict__ krot,
                const float* __restrict__ part1, int KS,
                const float* __restrict__ ck, const float* __restrict__ cv,
                const int* __restrict__ spp, float* __restrict__ attnp) {
    const int bkv = blockIdx.x;
    const int b = bkv >> 3, kv = bkv & 7;
    const int c = blockIdx.y;
    const int t = threadIdx.x;
    int lo, hi, cur;
    window_of(spp[0], lo, hi, cur);
    const int n = hi - lo;
    const int base0 = c * CH;
    if (base0 >= n) return;                       // block-uniform exit
    const int nc = (n - base0 < CH) ? (n - base0) : CH;
    const size_t kvoff = (size_t)(b * NKV + kv) * SW * HD;
    const float scale = 0.08838834764831845f;     // 1/sqrt(128)

    __shared__ float q_lds[GROUP * HD];           // 2KB
    __shared__ float scl[GROUP * CHP];            // 8.25KB scores -> probs (padded)
    __shared__ float vnew[HD];                    // 0.5KB
    __shared__ float mg[GROUP], lg[GROUP];
    __shared__ float pp[4][GROUP][HD];            // 8KB

    {
        const size_t qoff = ((size_t)b * NH + kv * GROUP) * HD;
        q_lds[t]       = qrot[qoff + t];
        q_lds[256 + t] = qrot[qoff + 256 + t];
    }
    if (t < HD) {   // vnew = sum over K-split slices (L2-resident)
        const float* vsrc = part1 + (size_t)b * NQKV + (size_t)(NH + NKV) * HD + kv * HD + t;
        float s = 0.f;
        for (int i = 0; i < KS; ++i) s += vsrc[(size_t)i * 32 * NQKV];
        vnew[t] = s;
    }
    __syncthreads();

    // ---- scores: 8 lanes per position; q hoisted to registers (zero LDS in loop) ----
    {
        const int dsl  = t & 7;                   // d-slice: d = j*32 + dsl*4
        const int posw = (t >> 3) & 7;            // position within wave's 8
        const int w    = t >> 6;                  // wave id
        float4 qreg[GROUP][4];
        #pragma unroll
        for (int g = 0; g < GROUP; ++g)
            #pragma unroll
            for (int j = 0; j < 4; ++j)
                qreg[g][j] = *(const float4*)&q_lds[g*HD + j*32 + dsl*4];

        const float* krow = krot + ((size_t)b * NKV + kv) * HD;
        #pragma unroll 1
        for (int it = 0; it < CH/32; ++it) {      // 16 iters, 32 positions/block each
            const int r = it*32 + w*8 + posw;
            const bool valid = (r < nc);
            float s0 = 0.f, s1 = 0.f, s2 = 0.f, s3 = 0.f;
            if (valid) {
                const int p = lo + base0 + r;
                const float* kbase = (p == cur) ? krow : (ck + kvoff + (size_t)p * HD);
                #pragma unroll
                for (int j = 0; j < 4; ++j) {
                    float4 kk = *(const float4*)&kbase[j*32 + dsl*4];
                    s0 += kk.x*qreg[0][j].x + kk.y*qreg[0][j].y + kk.z*qreg[0][j].z + kk.w*qreg[0][j].w;
                    s1 += kk.x*qreg[1][j].x + kk.y*qreg[1][j].y + kk.z*qreg[1][j].z + kk.w*qreg[1][j].w;
                    s2 += kk.x*qreg[2][j].x + kk.y*qreg[2][j].y + kk.z*qreg[2][j].z + kk.w*qreg[2][j].w;
                    s3 += kk.x*qreg[3][j].x + kk.y*qreg[3][j].y + kk.z*qreg[3][j].z + kk.w*qreg[3][j].w;
                }
            }
            // reduce across the 8 d-slice lanes
            s0 += __shfl_xor(s0, 1); s0 += __shfl_xor(s0, 2); s0 += __shfl_xor(s0, 4);
            s1 += __shfl_xor(s1, 1); s1 += __shfl_xor(s1, 2); s1 += __shfl_xor(s1, 4);
            s2 += __shfl_xor(s2, 1); s2 += __shfl_xor(s2, 2); s2 += __shfl_xor(s2, 4);
            s3 += __shfl_xor(s3, 1); s3 += __shfl_xor(s3, 2); s3 += __shfl_xor(s3, 4);
            float sg = (dsl == 0) ? s0 : (dsl == 1) ? s1 : (dsl == 2) ? s2 : s3;
            if (dsl < GROUP)
                scl[dsl * CHP + r] = valid ? sg * scale : -3.0e38f;
        }
    }
    __syncthreads();

    // ---- softmax partials: wave w reduces group w ----
    {
        const int w = t >> 6, l = t & 63;
        float v[8];
        float m = -3.0e38f;
        #pragma unroll
        for (int j = 0; j < 8; ++j) {
            v[j] = scl[w*CHP + l + 64*j];
            m = fmaxf(m, v[j]);
        }
        #pragma unroll
        for (int off = 32; off; off >>= 1) m = fmaxf(m, __shfl_xor(m, off));
        float ss = 0.f;
        #pragma unroll
        for (int j = 0; j < 8; ++j) {
            float e = __expf(v[j] - m);
            scl[w*CHP + l + 64*j] = e;
            ss += e;
        }
        #pragma unroll
        for (int off = 32; off; off >>= 1) ss += __shfl_xor(ss, off);
        if (l == 0) { mg[w] = m; lg[w] = ss; }
    }
    __syncthreads();

    // ---- partial PV: wave rg owns contiguous rows [rg*128, +128); probs via b128 broadcast ----
    {
        const int d2 = (t & 63) * 2, rg = t >> 6;
        const int r0 = rg * (CH/4);
        const float2 vn2 = *(const float2*)&vnew[d2];
        float a0[GROUP], a1[GROUP];
        #pragma unroll
        for (int g = 0; g < GROUP; ++g) { a0[g] = 0.f; a1[g] = 0.f; }
        #pragma unroll 1
        for (int i = 0; i < CH/16; ++i) {         // 32 iters, 4 rows each
            const int r = r0 + i*4;
            float4 pr[GROUP];
            #pragma unroll
            for (int g = 0; g < GROUP; ++g)
                pr[g] = *(const float4*)&scl[g*CHP + r];
            #pragma unroll
            for (int k = 0; k < 4; ++k) {
                const int rr = r + k;
                const int p = lo + base0 + rr;
                float2 v;
                if (rr >= nc)      v = make_float2(0.f, 0.f);
                else if (p == cur) v = vn2;
                else               v = *(const float2*)&cv[kvoff + (size_t)p * HD + d2];
                const float p0 = (k == 0) ? pr[0].x : (k == 1) ? pr[0].y : (k == 2) ? pr[0].z : pr[0].w;
                const float p1 = (k == 0) ? pr[1].x : (k == 1) ? pr[1].y : (k == 2) ? pr[1].z : pr[1].w;
                const float p2 = (k == 0) ? pr[2].x : (k == 1) ? pr[2].y : (k == 2) ? pr[2].z : pr[2].w;
                const float p3 = (k == 0) ? pr[3].x : (k == 1) ? pr[3].y : (k == 2) ? pr[3].z : pr[3].w;
                a0[0] += p0 * v.x; a1[0] += p0 * v.y;
                a0[1] += p1 * v.x; a1[1] += p1 * v.y;
                a0[2] += p2 * v.x; a1[2] += p2 * v.y;
                a0[3] += p3 * v.x; a1[3] += p3 * v.y;
            }
        }
        #pragma unroll
        for (int g = 0; g < GROUP; ++g) {
            pp[rg][g][d2]     = a0[g];
            pp[rg][g][d2 + 1] = a1[g];
        }
    }
    __syncthreads();
    {
        float* op = attnp + ((size_t)bkv * NCH + c) * 520;
        #pragma unroll
        for (int j = 0; j < 2; ++j) {
            int v = t + 256*j;
            int g = v >> 7, d = v & 127;
            op[g * HD + d] = pp[0][g][d] + pp[1][g][d] + pp[2][g][d] + pp[3][g][d];
        }
        if (t < GROUP) {
            op[512 + t] = mg[t];
            op[516 + t] = lg[t];
        }
    }
}

// merge chunk partials: out = sum_c exp(m_c - M) o_c / sum_c exp(m_c - M) l_c
__global__ __launch_bounds__(512)
void attn_reduce(const float* __restrict__ attnp, const int* __restrict__ spp,
                 float* __restrict__ aout) {
    const int bkv = blockIdx.x;
    const int b = bkv >> 3, kv = bkv & 7;
    const int g = threadIdx.x >> 7, d = threadIdx.x & 127;
    int lo, hi, cur;
    window_of(spp[0], lo, hi, cur);
    const int n = hi - lo;
    const int nch = (n + CH - 1) / CH;
    float M = -3.0e38f;
    for (int c = 0; c < nch; ++c)
        M = fmaxf(M, attnp[((size_t)bkv * NCH + c) * 520 + 512 + g]);
    float L = 0.f, O = 0.f;
    for (int c = 0; c < nch; ++c) {
        const float* op = attnp + ((size_t)bkv * NCH + c) * 520;
        float w = __expf(op[512 + g] - M);
        L += w * op[516 + g];
        O += w * op[g * HD + d];
    }
    aout[(size_t)b * NH * HD + (size_t)(kv * GROUP + g) * HD + d] = O / L;
}

// ---------------- fallback single-block attention (known-good round-6 path) ----------------
__global__ __launch_bounds__(512)
void attn_kernel(const float* __restrict__ qrot, const float* __restrict__ krot,
                 const float* __restrict__ qkv,
                 const float* __restrict__ ck, const float* __restrict__ cv,
                 const int* __restrict__ spp, float* __restrict__ aout) {
    const int b = blockIdx.x >> 3, kv = blockIdx.x & 7;
    const int t = threadIdx.x;
    int lo, hi, cur;
    window_of(spp[0], lo, hi, cur);
    const int n = hi - lo;
    const size_t kvoff = (size_t)(b * NKV + kv) * SW * HD;
    const float scale = 0.08838834764831845f;

    __shared__ float sc[GROUP * 2304];
    __shared__ float q_lds[GROUP * HD];
    __shared__ float redb[512];
    __shared__ float ssum_s[GROUP];

    q_lds[t] = qrot[((size_t)b * NH + kv * GROUP) * HD + t];
    __syncthreads();

    for (int i = t; i < n; i += 512) {
        int p = lo + i;
        float s[GROUP] = {0.f, 0.f, 0.f, 0.f};
        if (p == cur) {
            const float* kr = krot + ((size_t)b * NKV + kv) * HD;
            for (int d = 0; d < HD; ++d) {
                float kd = kr[d];
                #pragma unroll
                for (int g = 0; g < GROUP; ++g) s[g] += kd * q_lds[g * HD + d];
            }
        } else {
            const float* kp = ck + kvoff + (size_t)p * HD;
            for (int c = 0; c < 32; ++c) {
                float4 kk = ((const float4*)kp)[c];
                #pragma unroll
                for (int g = 0; g < GROUP; ++g)
                    s[g] += kk.x * q_lds[g * HD + c * 4] + kk.y * q_lds[g * HD + c * 4 + 1]
                          + kk.z * q_lds[g * HD + c * 4 + 2] + kk.w * q_lds[g * HD + c * 4 + 3];
            }
        }
        #pragma unroll
        for (int g = 0; g < GROUP; ++g)
            sc[g * 2304 + i] = s[g] * scale;
    }
    __syncthreads();

    for (int g = 0; g < GROUP; ++g) {
        float m = -3.0e38f;
        for (int i = t; i < n; i += 512) m = fmaxf(m, sc[g * 2304 + i]);
        redb[t] = m;
        __syncthreads();
        for (int w = 256; w > 0; w >>= 1) {
            if (t < w) redb[t] = fmaxf(redb[t], redb[t + w]);
            __syncthreads();
        }
        float mx = redb[0];
        __syncthreads();
        float s = 0.f;
        for (int i = t; i < n; i += 512) {
            float e = __expf(sc[g * 2304 + i] - mx);
            sc[g * 2304 + i] = e;
            s += e;
        }
        redb[t] = s;
        __syncthreads();
        for (int w = 256; w > 0; w >>= 1) {
            if (t < w) redb[t] += redb[t + w];
            __syncthreads();
        }
        if (t == 0) ssum_s[g] = redb[0];
        __syncthreads();
    }

    {
        const int g = t >> 7, d = t & 127;
        const float vn = qkv[(size_t)b * NQKV + (size_t)(NH + NKV) * HD + kv * HD + d];
        float acc = 0.f;
        for (int r = 0; r < n; ++r) {
            int p = lo + r;
            float v = (p == cur) ? vn : cv[kvoff + (size_t)p * HD + d];
            acc += sc[g * 2304 + r] * v;
        }
        aout[(size_t)b * NH * HD + (size_t)(kv * GROUP + g) * HD + d] = acc / ssum_s[g];
    }
}

extern "C" void kernel_launch(void* const* d_in, const int* in_sizes, int n_in,
                              void* d_out, int out_size, void* d_ws, size_t ws_size,
                              hipStream_t stream) {
    (void)out_size;
    static const long long CS[8] = {131072LL, 524288LL, 4194304LL, 134217728LL,
                                    134217728LL, 25165824LL, 16777216LL, 1LL};
    const void* Pp[8];
    bool canonical = (n_in == 8);
    if (canonical)
        for (int i = 0; i < 8; ++i)
            if ((long long)in_sizes[i] != CS[i]) { canonical = false; break; }
    if (canonical) {
        for (int i = 0; i < 8; ++i) Pp[i] = d_in[i];
    } else {
        bool used[64] = {false};
        for (int j = 0; j < 8; ++j) {
            Pp[j] = d_in[0];
            for (int i = 0; i < n_in && i < 64; ++i)
                if (!used[i] && (long long)in_sizes[i] == CS[j]) { used[i] = true; Pp[j] = d_in[i]; break; }
        }
    }

    const float* x    = (const float*)Pp[0];
    const float* rot  = (const float*)Pp[1];
    const float* ck   = (const float*)Pp[3];
    const float* cv   = (const float*)Pp[4];
    const float* wqkv = (const float*)Pp[5];
    const float* wo   = (const float*)Pp[6];
    const int*   sp   = (const int*)Pp[7];

    float* qkv  = (float*)d_ws;                       // 32*6144 (fallback only)
    float* qrot = qkv  + (size_t)BB*NQKV;             // 32*32*128
    float* krot = qrot + (size_t)BB*NH*HD;            // 32*8*128
    float* aout = krot + (size_t)BB*NKV*HD;           // 32*4096
    float* attnp= aout + (size_t)BB*NH*HD;            // 256*8*520
    float* part1= attnp + (size_t)BB*NKV*NCH*520;

    const size_t head_bytes = ((size_t)BB*(NQKV + NH*HD + NKV*HD + NH*HD)
                               + (size_t)BB*NKV*NCH*520) * 4;
    const size_t p1_bytes   = (size_t)32*32*NQKV*4;   // KS1=32 slices
    const size_t p2_bytes   = (size_t)32*32*HIDDEN*4; // KS2=32 slices

    if (ws_size >= head_bytes + p1_bytes + p2_bytes) {
        const int KS1 = 32, KS2 = 32;
        float* part2 = part1 + (size_t)KS1*32*NQKV;

        gemm_f32<NQKV><<<dim3(NQKV/128, KS1), 256, 0, stream>>>(x, wqkv, part1, HIDDEN/KS1);
        rope_red<<<dim3(BB, 5), 256, 0, stream>>>(part1, KS1, rot, qrot, krot);
        attn_chunk<<<dim3(BB*NKV, NCH), 256, 0, stream>>>(qrot, krot, part1, KS1, ck, cv, sp, attnp);
        attn_reduce<<<BB*NKV, 512, 0, stream>>>(attnp, sp, aout);
        gemm_f32<HIDDEN><<<dim3(HIDDEN/128, KS2), 256, 0, stream>>>(aout, wo, part2, HIDDEN/KS2);
        reduce_part<HIDDEN><<<(BB*HIDDEN + 255)/256, 256, 0, stream>>>(part2, (float*)d_out, KS2);
    } else {
        // fallback: small-ws path
        size_t per_ks = (size_t)32*(NQKV + HIDDEN) * 4;
        size_t avail = (ws_size > head_bytes) ? ws_size - head_bytes : 0;
        int KS = 1;
        if      (avail >= 8*per_ks) KS = 8;
        else if (avail >= 4*per_ks) KS = 4;
        else if (avail >= 2*per_ks) KS = 2;
        float* part2 = part1 + (size_t)KS*32*NQKV;

        gemm_f32<NQKV><<<dim3(NQKV/128, KS), 256, 0, stream>>>(x, wqkv, part1, HIDDEN/KS);
        reduce_part<NQKV><<<(BB*NQKV + 255)/256, 256, 0, stream>>>(part1, qkv, KS);
        rope_red<<<dim3(BB, 5), 256, 0, stream>>>(part1, KS, rot, qrot, krot);
        attn_kernel<<<BB*NKV, 512, 0, stream>>>(qrot, krot, qkv, ck, cv, sp, aout);
        gemm_f32<HIDDEN><<<dim3(HIDDEN/128, KS), 256, 0, stream>>>(aout, wo, part2, HIDDEN/KS);
        reduce_part<HIDDEN><<<(BB*HIDDEN + 255)/256, 256, 0, stream>>>(part2, (float*)d_out, KS);
    }
}